// Round 5
// baseline (106.460 us; speedup 1.0000x reference)
//
#include <hip/hip_runtime.h>
#include <hip/hip_bf16.h>

#define NTHREADS 256
#define N_ATOMS 1024
#define HIDDEN 64

// One block per atom (B*N = 8192 blocks), 256 threads.  Identical to the
// round-2 kernel (best so far) EXCEPT phase 2: the 34->64->64->64 MLP now
// runs split-k on all 256 threads -- thread = (unit t = tid&63, k-chunk
// g = tid>>6, k = g, g+4, ...), LDS partial reduction per layer.  This
// quarters the dependent-chain length (16 chained FMAs per layer instead
// of 64) and uses all 4 waves instead of 1.
__global__ __launch_bounds__(NTHREADS) void LocalFeatureEncoder_40063454937486_kernel(
    const float* __restrict__ pos,    // [B,N,3]
    const int*   __restrict__ types,  // [B,N]
    const float* __restrict__ W1,     // [34,64]
    const float* __restrict__ b1,     // [64]
    const float* __restrict__ W2,     // [64,64]
    const float* __restrict__ b2,     // [64]
    const float* __restrict__ W3,     // [64,64]
    const float* __restrict__ b3,     // [64]
    float*       __restrict__ out)    // [B,N,64]
{
    const int a    = blockIdx.x;          // b*N + i
    const int bidx = a >> 10;             // N = 1024
    const int i    = a & (N_ATOMS - 1);
    const int tid  = threadIdx.x;
    const int lane = tid & 63;
    const int wav  = tid >> 6;

    __shared__ float qd [N_ATOMS];        // queue: distance
    __shared__ float qm0[N_ATOMS];        // queue: cutv * (type==0)
    __shared__ float qm1[N_ATOMS];        // queue: cutv * (type==1)
    __shared__ float partial[4 * 64];     // env partials / MLP split-k partials
    __shared__ float feats[64];           // 34 used
    __shared__ float h1s[64];             // h1 / h2 ping-pong
    __shared__ float h2s[64];
    __shared__ int   cnt;

    if (tid == 0) cnt = 0;

    const float* posb = pos + (size_t)bidx * N_ATOMS * 3;
    const int*   typb = types + (size_t)bidx * N_ATOMS;

    const float xi = posb[i * 3 + 0];
    const float yi = posb[i * 3 + 1];
    const float zi = posb[i * 3 + 2];

    __syncthreads();                      // cnt = 0 visible

    // ---------- phase 1a: distances + stream compaction ----------
#pragma unroll
    for (int it = 0; it < N_ATOMS / NTHREADS; ++it) {
        const int j = tid + it * NTHREADS;
        const float px = posb[j * 3 + 0];
        const float py = posb[j * 3 + 1];
        const float pz = posb[j * 3 + 2];
        const int   tj = typb[j];
        const float dx = xi - px, dy = yi - py, dz = zi - pz;
        const float sq = dx * dx + dy * dy + dz * dz;
        const bool pred = (j != i) && (sq < 6.25f);

        const unsigned long long mask = __ballot(pred);
        int base = 0;
        if (lane == 0 && mask) base = atomicAdd(&cnt, (int)__popcll(mask));
        base = __shfl(base, 0, 64);       // convergent broadcast
        if (pred) {
            const float d  = sqrtf(sq);
            const float x  = d * 0.4f;    // d / 2.5
            const float x3 = x * x * x;
            const float cutv = 1.0f + x3 * (-10.0f + x * (15.0f - 6.0f * x));
            const int idx = base + (int)__popcll(mask & ((1ull << lane) - 1ull));
            qd [idx] = d;
            qm0[idx] = (tj == 0) ? cutv : 0.0f;
            qm1[idx] = (tj == 0) ? 0.0f : cutv;
        }
    }
    __syncthreads();
    const int n = cnt;

    // ---------- phase 1b: feature-parallel RBF accumulation ----------
    {
        const int p = tid >> 5;               // pair slot 0..7
        const int f = tid & 31;               // feature  0..31 (= r*2 + s)
        const int r = f >> 1;
        const int s = f & 1;
        const float c = (float)r * (2.5f / 15.0f);
        const float inv_w2 = 36.0f;           // 1/((2.5/15)^2 + 1e-12)
        const float* __restrict__ qm = (s == 0) ? qm0 : qm1;

        float acc = 0.0f;
        for (int e = p; e < n; e += 8) {
            const float d    = qd[e];
            const float m    = qm[e];
            const float diff = d - c;
            acc += m * __expf(-(diff * diff) * inv_w2);
        }
        acc += __shfl_xor(acc, 32, 64);       // combine the 2 pair-slots per wave
        if (lane < 32) partial[wav * 32 + f] = acc;
        if (tid == 0) {
            const int ti = typb[i];
            feats[0] = (ti == 0) ? 1.0f : 0.0f;
            feats[1] = (ti == 1) ? 1.0f : 0.0f;
        }
    }
    __syncthreads();
    if (tid < 32)
        feats[2 + tid] = partial[tid] + partial[32 + tid] + partial[64 + tid] + partial[96 + tid];
    __syncthreads();

    // ---------- phase 2: MLP, split-k on all 256 threads ----------
    const int t = tid & 63;                   // output unit
    const int g = wav;                        // k-chunk (stride-4 over k)

    // layer 1: 34 -> 64, SiLU
    {
        float ps = 0.0f;
        for (int k = g; k < 34; k += 4) ps += feats[k] * W1[k * HIDDEN + t];
        partial[g * 64 + t] = ps;
    }
    __syncthreads();
    if (tid < HIDDEN) {
        float h = b1[tid] + partial[tid] + partial[64 + tid]
                + partial[128 + tid] + partial[192 + tid];
        h = h / (1.0f + __expf(-h));
        h1s[tid] = h;
    }
    __syncthreads();

    // layer 2: 64 -> 64, SiLU
    {
        float ps = 0.0f;
#pragma unroll
        for (int k = g; k < HIDDEN; k += 4) ps += h1s[k] * W2[k * HIDDEN + t];
        partial[g * 64 + t] = ps;
    }
    __syncthreads();
    if (tid < HIDDEN) {
        float h = b2[tid] + partial[tid] + partial[64 + tid]
                + partial[128 + tid] + partial[192 + tid];
        h = h / (1.0f + __expf(-h));
        h2s[tid] = h;
    }
    __syncthreads();

    // layer 3: 64 -> 64, linear
    {
        float ps = 0.0f;
#pragma unroll
        for (int k = g; k < HIDDEN; k += 4) ps += h2s[k] * W3[k * HIDDEN + t];
        partial[g * 64 + t] = ps;
    }
    __syncthreads();
    if (tid < HIDDEN) {
        const float o = b3[tid] + partial[tid] + partial[64 + tid]
                      + partial[128 + tid] + partial[192 + tid];
        out[(size_t)a * HIDDEN + tid] = o;
    }
}

extern "C" void kernel_launch(void* const* d_in, const int* in_sizes, int n_in,
                              void* d_out, int out_size, void* d_ws, size_t ws_size,
                              hipStream_t stream) {
    const float* pos   = (const float*)d_in[0];
    const int*   types = (const int*)d_in[1];
    const float* W1    = (const float*)d_in[2];
    const float* b1    = (const float*)d_in[3];
    const float* W2    = (const float*)d_in[4];
    const float* b2    = (const float*)d_in[5];
    const float* W3    = (const float*)d_in[6];
    const float* b3    = (const float*)d_in[7];
    float*       out   = (float*)d_out;

    const int BN = in_sizes[1];           // B*N = 8192

    LocalFeatureEncoder_40063454937486_kernel<<<BN, NTHREADS, 0, stream>>>(
        pos, types, W1, b1, W2, b2, W3, b3, out);
}

// Round 6
// 89.012 us; speedup vs baseline: 1.1960x; 1.1960x over previous
//
#include <hip/hip_runtime.h>
#include <hip/hip_bf16.h>

#define NTHREADS 256
#define N_ATOMS 1024
#define HIDDEN 64

// One block per atom (B*N = 8192 blocks), 256 threads.  Round-2 skeleton
// (best measured: ~33 us) with ONE change: phase 1a loads each thread's 4
// neighbors via 3 aligned float4 + 1 int4 (coalesced dwordx4, issued before
// the cnt barrier), then runs 4 ballot/compact rounds from registers --
// replacing 16 stride-3 scalar loads + 4 strided loop iterations.
__global__ __launch_bounds__(NTHREADS) void LocalFeatureEncoder_40063454937486_kernel(
    const float* __restrict__ pos,    // [B,N,3]
    const int*   __restrict__ types,  // [B,N]
    const float* __restrict__ W1,     // [34,64]
    const float* __restrict__ b1,     // [64]
    const float* __restrict__ W2,     // [64,64]
    const float* __restrict__ b2,     // [64]
    const float* __restrict__ W3,     // [64,64]
    const float* __restrict__ b3,     // [64]
    float*       __restrict__ out)    // [B,N,64]
{
    const int a    = blockIdx.x;          // b*N + i
    const int bidx = a >> 10;             // N = 1024
    const int i    = a & (N_ATOMS - 1);
    const int tid  = threadIdx.x;
    const int lane = tid & 63;
    const int wav  = tid >> 6;

    __shared__ float qd [N_ATOMS];        // queue: distance
    __shared__ float qm0[N_ATOMS];        // queue: cutv * (type==0)
    __shared__ float qm1[N_ATOMS];        // queue: cutv * (type==1)
    __shared__ float partial[4 * 32];
    __shared__ float feats[64];           // 34 used
    __shared__ float h1s[64];
    __shared__ int   cnt;

    const float* pf   = pos + (size_t)bidx * (N_ATOMS * 3);
    const int*   typb = types + (size_t)bidx * N_ATOMS;

    // ---- issue all neighbor loads BEFORE the barrier (latency overlap) ----
    const float4 p0 = *(const float4*)(pf + tid * 12);
    const float4 p1 = *(const float4*)(pf + tid * 12 + 4);
    const float4 p2 = *(const float4*)(pf + tid * 12 + 8);
    const int4   tv = *(const int4*)(typb + tid * 4);

    const float xi = pf[i * 3 + 0];
    const float yi = pf[i * 3 + 1];
    const float zi = pf[i * 3 + 2];

    if (tid == 0) cnt = 0;
    __syncthreads();                      // cnt = 0 visible

    // ---------- phase 1a: distances + stream compaction (4 rounds) ----------
    {
        // atom q of this thread: coords at floats [q*3 .. q*3+2] of the 12
        const float px[4] = {p0.x, p0.w, p1.z, p2.y};
        const float py[4] = {p0.y, p1.x, p1.w, p2.z};
        const float pz[4] = {p0.z, p1.y, p2.x, p2.w};
        const int   tj[4] = {tv.x, tv.y, tv.z, tv.w};

#pragma unroll
        for (int q = 0; q < 4; ++q) {
            const int j = tid * 4 + q;
            const float dx = xi - px[q], dy = yi - py[q], dz = zi - pz[q];
            const float sq = dx * dx + dy * dy + dz * dz;
            const bool pred = (j != i) && (sq < 6.25f);

            const unsigned long long mask = __ballot(pred);
            int base = 0;
            if (lane == 0 && mask) base = atomicAdd(&cnt, (int)__popcll(mask));
            base = __shfl(base, 0, 64);   // convergent broadcast
            if (pred) {
                const float d  = sqrtf(sq);
                const float x  = d * 0.4f;    // d / 2.5
                const float x3 = x * x * x;
                const float cutv = 1.0f + x3 * (-10.0f + x * (15.0f - 6.0f * x));
                const int idx = base + (int)__popcll(mask & ((1ull << lane) - 1ull));
                qd [idx] = d;
                qm0[idx] = (tj[q] == 0) ? cutv : 0.0f;
                qm1[idx] = (tj[q] == 0) ? 0.0f : cutv;
            }
        }
    }
    __syncthreads();
    const int n = cnt;

    // ---------- phase 1b: feature-parallel RBF accumulation ----------
    {
        const int p = tid >> 5;               // pair slot 0..7
        const int f = tid & 31;               // feature  0..31 (= r*2 + s)
        const int r = f >> 1;
        const int s = f & 1;
        const float c = (float)r * (2.5f / 15.0f);
        const float inv_w2 = 36.0f;           // 1/((2.5/15)^2 + 1e-12)
        const float* __restrict__ qm = (s == 0) ? qm0 : qm1;

        float acc = 0.0f;
        for (int e = p; e < n; e += 8) {
            const float d    = qd[e];
            const float m    = qm[e];
            const float diff = d - c;
            acc += m * __expf(-(diff * diff) * inv_w2);
        }
        acc += __shfl_xor(acc, 32, 64);       // combine the 2 pair-slots per wave
        if (lane < 32) partial[wav * 32 + f] = acc;
        if (tid == 0) {
            const int ti = typb[i];
            feats[0] = (ti == 0) ? 1.0f : 0.0f;
            feats[1] = (ti == 1) ? 1.0f : 0.0f;
        }
    }
    __syncthreads();
    if (tid < 32)
        feats[2 + tid] = partial[tid] + partial[32 + tid] + partial[64 + tid] + partial[96 + tid];
    __syncthreads();

    // ---------- phase 2: MLP (threads 0..63), round-2 version ----------
    if (tid < HIDDEN) {
        float h = b1[tid];
#pragma unroll
        for (int k = 0; k < 34; k++) h += feats[k] * W1[k * HIDDEN + tid];
        h = h / (1.0f + __expf(-h));
        h1s[tid] = h;
    }
    __syncthreads();
    if (tid < HIDDEN) {
        float h = b2[tid];
#pragma unroll
        for (int k = 0; k < HIDDEN; k++) h += h1s[k] * W2[k * HIDDEN + tid];
        h = h / (1.0f + __expf(-h));
        feats[tid] = h;
    }
    __syncthreads();
    if (tid < HIDDEN) {
        float o = b3[tid];
#pragma unroll
        for (int k = 0; k < HIDDEN; k++) o += feats[k] * W3[k * HIDDEN + tid];
        out[(size_t)a * HIDDEN + tid] = o;
    }
}

extern "C" void kernel_launch(void* const* d_in, const int* in_sizes, int n_in,
                              void* d_out, int out_size, void* d_ws, size_t ws_size,
                              hipStream_t stream) {
    const float* pos   = (const float*)d_in[0];
    const int*   types = (const int*)d_in[1];
    const float* W1    = (const float*)d_in[2];
    const float* b1    = (const float*)d_in[3];
    const float* W2    = (const float*)d_in[4];
    const float* b2    = (const float*)d_in[5];
    const float* W3    = (const float*)d_in[6];
    const float* b3    = (const float*)d_in[7];
    float*       out   = (float*)d_out;

    const int BN = in_sizes[1];           // B*N = 8192

    LocalFeatureEncoder_40063454937486_kernel<<<BN, NTHREADS, 0, stream>>>(
        pos, types, W1, b1, W2, b2, W3, b3, out);
}